// Round 8
// baseline (658.239 us; speedup 1.0000x reference)
//
#include <hip/hip_runtime.h>
#include <hip/hip_fp16.h>
#include <math.h>

#define NEG_SLOPE 0.2f
#define NPB 256   // nodes per bucket (dst >> 8)
#define MAXB 512  // max buckets => supports n_nodes <= 131072 (bench: 100000 -> 391)
#define A1_BS 1024
#define BCAP 10240  // LDS sort capacity (records); avg bucket 8192, sigma ~90

static __device__ __forceinline__ float leaky(float x) { return fmaxf(x, NEG_SLOPE * x); }

// ---------------- misc ----------------
__global__ void k_zero(int* p, int n) {
    int i = blockIdx.x * blockDim.x + threadIdx.x;
    if (i < n) p[i] = 0;
}

// ---------------- bucketed counting sort CSR build ----------------
// Buckets = 256-node ranges. All heavy atomics are LDS-local; all heavy global
// writes are to per-block-exclusive contiguous ranges. Staging record is ONE
// 8B int2: word0 = src | (dst&255)<<20, word1 = ew bits.

// Pass A0: global bucket histogram (LDS pre-aggregated).
__global__ __launch_bounds__(256) void k_bcount(const int* __restrict__ dst,
                                                int* __restrict__ bcnt, int n_edges, int nb) {
    __shared__ int h[MAXB];
    for (int i = threadIdx.x; i < nb; i += blockDim.x) h[i] = 0;
    __syncthreads();
    int stride = gridDim.x * blockDim.x;
    for (int e = blockIdx.x * blockDim.x + threadIdx.x; e < n_edges; e += stride)
        atomicAdd(&h[dst[e] >> 8], 1);
    __syncthreads();
    for (int i = threadIdx.x; i < nb; i += blockDim.x)
        if (h[i]) atomicAdd(&bcnt[i], h[i]);
}

// Bucket exclusive scan (nb <= MAXB, single block).
__global__ __launch_bounds__(MAXB) void k_bscan(const int* __restrict__ bcnt,
                                                int* __restrict__ boffB,
                                                int* __restrict__ bcur, int nb) {
    __shared__ int s[MAXB];
    int t = threadIdx.x;
    int v = (t < nb) ? bcnt[t] : 0;
    s[t] = v;
    __syncthreads();
    for (int off = 1; off < MAXB; off <<= 1) {
        int x = (t >= off) ? s[t - off] : 0;
        __syncthreads();
        s[t] += x;
        __syncthreads();
    }
    if (t < nb) {
        int ex = s[t] - v;
        boffB[t] = ex;
        bcur[t] = ex;
    }
}

// Pass A1: bin edges into bucket-grouped packed staging (one int2 per edge).
__global__ __launch_bounds__(A1_BS) void k_bin(const int* __restrict__ src,
                                               const int* __restrict__ dst,
                                               const float* __restrict__ ew,
                                               int* __restrict__ bcur,
                                               int2* __restrict__ recS,
                                               int n_edges, int chunk, int nb) {
    __shared__ int cnt[MAXB];
    __shared__ int base[MAXB];
    int t = threadIdx.x;
    int e0 = blockIdx.x * chunk;
    int e1 = e0 + chunk;
    if (e1 > n_edges) e1 = n_edges;
    for (int i = t; i < nb; i += A1_BS) cnt[i] = 0;
    __syncthreads();
    for (int e = e0 + t; e < e1; e += A1_BS) atomicAdd(&cnt[dst[e] >> 8], 1);
    __syncthreads();
    for (int i = t; i < nb; i += A1_BS) {
        int c = cnt[i];
        base[i] = c ? atomicAdd(&bcur[i], c) : 0;
        cnt[i] = 0;  // reuse as local rank cursor
    }
    __syncthreads();
    for (int e = e0 + t; e < e1; e += A1_BS) {
        int d = dst[e];
        int b = d >> 8;
        int p = base[b] + atomicAdd(&cnt[b], 1);
        recS[p] = make_int2(src[e] | ((d & (NPB - 1)) << 20), __float_as_int(ew[e]));
    }
}

// Pass B (fused): per-bucket SRC-BIN SORT -> dst hist -> in-LDS scan ->
// row_ptr -> placement. The src-bin LDS counting sort makes every CSR row
// approximately src-sorted: all concurrent k_edge waves then sweep feat[]
// low->high in lockstep (iteration j ~ quantile j/deg), shrinking the
// instantaneous gather working set from 25.6MB to an L2-sized window.
// Fallback (bucket > BCAP records): unsorted direct placement (correct,
// just loses the locality bonus).
__global__ __launch_bounds__(MAXB) void k_buildcsr(const int* __restrict__ boffB,
                                                   const int* __restrict__ bcnt,
                                                   const int2* __restrict__ recS,
                                                   int* __restrict__ row_ptr,
                                                   int2* __restrict__ csr,
                                                   int n_nodes, int n_edges) {
    __shared__ int2 buf[BCAP];   // 80KB sorted staging
    __shared__ int hsrc[MAXB];   // src-bin hist / cursor
    __shared__ int tmp[MAXB];
    __shared__ int hdst[NPB];
    __shared__ int cdst[NPB];
    int b = blockIdx.x;
    int t = threadIdx.x;
    for (int i = t; i < MAXB; i += MAXB) hsrc[i] = 0;
    if (t < NPB) hdst[t] = 0;
    __syncthreads();
    int off = boffB[b];
    int cnt = bcnt[b];
    int end = off + cnt;

    // pass 1: both histograms in one sweep of the staging slice
    for (int i = off + t; i < end; i += MAXB) {
        int x = recS[i].x;
        atomicAdd(&hsrc[(x & 0xFFFFF) >> 8], 1);
        atomicAdd(&hdst[(x >> 20) & (NPB - 1)], 1);
    }
    __syncthreads();

    // scan src-bin hist (512 wide) -> bucket-relative exclusive cursors
    int vs = hsrc[t];
    tmp[t] = vs;
    __syncthreads();
    for (int o = 1; o < MAXB; o <<= 1) {
        int x = (t >= o) ? tmp[t - o] : 0;
        __syncthreads();
        tmp[t] += x;
        __syncthreads();
    }
    hsrc[t] = tmp[t] - vs;  // exclusive, 0-based within bucket
    __syncthreads();

    // scan dst hist (256 wide) -> row_ptr + placement cursors
    int vd = (t < NPB) ? hdst[t] : 0;
    if (t < NPB) tmp[t] = vd;
    __syncthreads();
    for (int o = 1; o < NPB; o <<= 1) {
        int x = (t >= o && t < NPB) ? tmp[t - o] : 0;
        __syncthreads();
        if (t < NPB) tmp[t] += x;
        __syncthreads();
    }
    if (t < NPB) {
        int ex = tmp[t] - vd;
        int node = b * NPB + t;
        if (node < n_nodes) row_ptr[node] = off + ex;
        if (node == n_nodes - 1) row_ptr[n_nodes] = n_edges;
        cdst[t] = off + ex;
    }
    if (b == 0 && t < 8) csr[n_edges + t] = make_int2(0, 0);  // pad for clamped tail reads
    __syncthreads();

    if (cnt <= BCAP) {
        // pass 2: place records into LDS in src-bin-sorted order
        for (int i = off + t; i < end; i += MAXB) {
            int2 r = recS[i];
            int p = atomicAdd(&hsrc[(r.x & 0xFFFFF) >> 8], 1);
            buf[p] = r;
        }
        __syncthreads();
        // pass 3: stable-ish dst placement reading sorted buf sequentially
        for (int i = t; i < cnt; i += MAXB) {
            int2 r = buf[i];
            int p = atomicAdd(&cdst[(r.x >> 20) & (NPB - 1)], 1);
            csr[p] = make_int2(r.x & 0xFFFFF, r.y);
        }
    } else {
        // fallback: unsorted direct placement
        for (int i = off + t; i < end; i += MAXB) {
            int2 r = recS[i];
            int p = atomicAdd(&cdst[(r.x >> 20) & (NPB - 1)], 1);
            csr[p] = make_int2(r.x & 0xFFFFF, r.y);
        }
    }
}

// ---------------- GEMM + fused attention scores (streamed A) ----------------
// C is fp16 [n][128] (messages consumed only by k_edge's random gather --
// halving its bytes). All arithmetic, el/er, and layer outputs remain fp32.
__global__ __launch_bounds__(256) void k_gemm(const float* __restrict__ A,
                                              const float* __restrict__ B,
                                              __half* __restrict__ C,
                                              const float* __restrict__ al,
                                              const float* __restrict__ ar,
                                              float* __restrict__ el,
                                              float* __restrict__ er, int n) {
    __shared__ float Bs[128 * 64];  // Bs[k][c]
    int t = threadIdx.x;
    int row0 = blockIdx.x * 64;
    int colbase = blockIdx.y * 64;

    // stage B strip
    {
        int c0 = (t & 15) * 4;
        int kr = t >> 4;  // 0..15
        for (int it = 0; it < 8; ++it) {
            int k = kr + it * 16;
            float4 v = *(const float4*)(B + (size_t)k * 128 + colbase + c0);
            *(float4*)(Bs + k * 64 + c0) = v;
        }
    }
    __syncthreads();

    int r0 = row0 + (t >> 4) * 4;
    int c0 = (t & 15) * 4;
    const float* Ar0 = A + (size_t)((r0 + 0) < n ? (r0 + 0) : 0) * 128;
    const float* Ar1 = A + (size_t)((r0 + 1) < n ? (r0 + 1) : 0) * 128;
    const float* Ar2 = A + (size_t)((r0 + 2) < n ? (r0 + 2) : 0) * 128;
    const float* Ar3 = A + (size_t)((r0 + 3) < n ? (r0 + 3) : 0) * 128;

    float acc[4][4];
#pragma unroll
    for (int i = 0; i < 4; i++)
#pragma unroll
        for (int j = 0; j < 4; j++) acc[i][j] = 0.f;

#pragma unroll 2
    for (int k = 0; k < 128; k += 4) {
        float4 a0 = *(const float4*)(Ar0 + k);
        float4 a1 = *(const float4*)(Ar1 + k);
        float4 a2 = *(const float4*)(Ar2 + k);
        float4 a3 = *(const float4*)(Ar3 + k);
#pragma unroll
        for (int kk = 0; kk < 4; kk++) {
            float4 b = *(const float4*)(Bs + (k + kk) * 64 + c0);
            float e0 = kk == 0 ? a0.x : kk == 1 ? a0.y : kk == 2 ? a0.z : a0.w;
            float e1 = kk == 0 ? a1.x : kk == 1 ? a1.y : kk == 2 ? a1.z : a1.w;
            float e2 = kk == 0 ? a2.x : kk == 1 ? a2.y : kk == 2 ? a2.z : a2.w;
            float e3 = kk == 0 ? a3.x : kk == 1 ? a3.y : kk == 2 ? a3.z : a3.w;
            acc[0][0] = fmaf(e0, b.x, acc[0][0]); acc[0][1] = fmaf(e0, b.y, acc[0][1]);
            acc[0][2] = fmaf(e0, b.z, acc[0][2]); acc[0][3] = fmaf(e0, b.w, acc[0][3]);
            acc[1][0] = fmaf(e1, b.x, acc[1][0]); acc[1][1] = fmaf(e1, b.y, acc[1][1]);
            acc[1][2] = fmaf(e1, b.z, acc[1][2]); acc[1][3] = fmaf(e1, b.w, acc[1][3]);
            acc[2][0] = fmaf(e2, b.x, acc[2][0]); acc[2][1] = fmaf(e2, b.y, acc[2][1]);
            acc[2][2] = fmaf(e2, b.z, acc[2][2]); acc[2][3] = fmaf(e2, b.w, acc[2][3]);
            acc[3][0] = fmaf(e3, b.x, acc[3][0]); acc[3][1] = fmaf(e3, b.y, acc[3][1]);
            acc[3][2] = fmaf(e3, b.z, acc[3][2]); acc[3][3] = fmaf(e3, b.w, acc[3][3]);
        }
    }

#pragma unroll
    for (int i = 0; i < 4; i++) {
        int r = r0 + i;
        if (r < n) {
            __half2 h01 = __floats2half2_rn(acc[i][0], acc[i][1]);
            __half2 h23 = __floats2half2_rn(acc[i][2], acc[i][3]);
            union { __half2 h[2]; uint2 u; } cv;
            cv.h[0] = h01;
            cv.h[1] = h23;
            *(uint2*)(C + (size_t)r * 128 + colbase + c0) = cv.u;
        }
    }

    // fused el/er: strip covers heads 2*by, 2*by+1; 8 consecutive lanes share
    // (row group, head) -> shfl reduce. Computed from fp32 acc (full precision).
    {
        int hg = blockIdx.y * 2 + ((t >> 3) & 1);
        float4 a4 = *(const float4*)(al + hg * 32 + (t & 7) * 4);
        float4 b4 = *(const float4*)(ar + hg * 32 + (t & 7) * 4);
        float pel[4], per[4];
#pragma unroll
        for (int i = 0; i < 4; i++) {
            pel[i] = acc[i][0] * a4.x + acc[i][1] * a4.y + acc[i][2] * a4.z + acc[i][3] * a4.w;
            per[i] = acc[i][0] * b4.x + acc[i][1] * b4.y + acc[i][2] * b4.z + acc[i][3] * b4.w;
        }
#pragma unroll
        for (int m = 1; m < 8; m <<= 1) {
#pragma unroll
            for (int i = 0; i < 4; i++) {
                pel[i] += __shfl_xor(pel[i], m);
                per[i] += __shfl_xor(per[i], m);
            }
        }
        if ((t & 7) == 0) {
#pragma unroll
            for (int i = 0; i < 4; i++) {
                int r = r0 + i;
                if (r < n) {
                    el[(size_t)r * 4 + hg] = pel[i];
                    er[(size_t)r * 4 + hg] = per[i];
                }
            }
        }
    }
}

// ---------------- per-dst-node softmax + aggregate (fp16 gather) ----------
// Fetch-BW-bound at the random-gather ceiling (rounds 0-7); fp16 rows (256B)
// halved bytes and time; src-sorted rows (k_buildcsr) add L2 lockstep
// locality. Lane li reads 8B (uint2 = 4 halves); 32 lanes x 8B = 256B
// contiguous per edge.
__global__ __launch_bounds__(256) void k_edge(const int* __restrict__ row_ptr,
                                              const int2* __restrict__ csr,
                                              const __half* __restrict__ feat,
                                              const float* __restrict__ el,
                                              const float* __restrict__ er,
                                              const float* __restrict__ bias,
                                              float* __restrict__ out, int n) {
    int wv = threadIdx.x >> 6;
    int lane = threadIdx.x & 63;
    int sub = lane >> 5;   // which node of this wave's pair
    int li = lane & 31;    // feature lane
    int h = li >> 3;       // head
    int v = blockIdx.x * 8 + wv * 2 + sub;
    bool active = v < n;
    int vc = active ? v : n - 1;

    int start = row_ptr[vc];
    int end = active ? row_ptr[vc + 1] : start;
    float er_h = er[(size_t)vc * 4 + h];

    int myT = (end - start + 3) >> 2;
    int otherT = __shfl(myT, lane ^ 32);
    int maxT = myT > otherT ? myT : otherT;

    int last = end - 1;
    if (last < start) last = start;  // deg-0 half: clamped reads (csr pad is zeroed)

    float4 acc = make_float4(0.f, 0.f, 0.f, 0.f);
    float ssum = 0.f;

    for (int j = 0; j < maxT; ++j) {
        int i = start + j * 4;
        int i0 = i < last ? i : last;
        int i1 = i + 1 < last ? i + 1 : last;
        int i2 = i + 2 < last ? i + 2 : last;
        int i3 = i + 3 < last ? i + 3 : last;
        float m0 = (i < end) ? 1.f : 0.f;
        float m1 = (i + 1 < end) ? 1.f : 0.f;
        float m2 = (i + 2 < end) ? 1.f : 0.f;
        float m3 = (i + 3 < end) ? 1.f : 0.f;
        int2 c0 = csr[i0];
        int2 c1 = csr[i1];
        int2 c2 = csr[i2];
        int2 c3 = csr[i3];
        // all independent loads first (4-deep MLP)
        float el0 = el[(size_t)c0.x * 4 + h];
        float el1 = el[(size_t)c1.x * 4 + h];
        float el2 = el[(size_t)c2.x * 4 + h];
        float el3 = el[(size_t)c3.x * 4 + h];
        uint2 r0 = ((const uint2*)(feat + (size_t)c0.x * 128))[li];
        uint2 r1 = ((const uint2*)(feat + (size_t)c1.x * 128))[li];
        uint2 r2 = ((const uint2*)(feat + (size_t)c2.x * 128))[li];
        uint2 r3 = ((const uint2*)(feat + (size_t)c3.x * 128))[li];
        float p0 = m0 * __expf(leaky(el0 + er_h));
        float p1 = m1 * __expf(leaky(el1 + er_h));
        float p2 = m2 * __expf(leaky(el2 + er_h));
        float p3 = m3 * __expf(leaky(el3 + er_h));
        ssum += (p0 + p1) + (p2 + p3);
        float w0 = p0 * __int_as_float(c0.y);
        float w1 = p1 * __int_as_float(c1.y);
        float w2 = p2 * __int_as_float(c2.y);
        float w3 = p3 * __int_as_float(c3.y);
        float2 a0 = __half22float2(*(__half2*)&r0.x);
        float2 b0 = __half22float2(*(__half2*)&r0.y);
        float2 a1 = __half22float2(*(__half2*)&r1.x);
        float2 b1 = __half22float2(*(__half2*)&r1.y);
        float2 a2 = __half22float2(*(__half2*)&r2.x);
        float2 b2 = __half22float2(*(__half2*)&r2.y);
        float2 a3 = __half22float2(*(__half2*)&r3.x);
        float2 b3 = __half22float2(*(__half2*)&r3.y);
        acc.x = fmaf(w0, a0.x, acc.x); acc.y = fmaf(w0, a0.y, acc.y);
        acc.z = fmaf(w0, b0.x, acc.z); acc.w = fmaf(w0, b0.y, acc.w);
        acc.x = fmaf(w1, a1.x, acc.x); acc.y = fmaf(w1, a1.y, acc.y);
        acc.z = fmaf(w1, b1.x, acc.z); acc.w = fmaf(w1, b1.y, acc.w);
        acc.x = fmaf(w2, a2.x, acc.x); acc.y = fmaf(w2, a2.y, acc.y);
        acc.z = fmaf(w2, b2.x, acc.z); acc.w = fmaf(w2, b2.y, acc.w);
        acc.x = fmaf(w3, a3.x, acc.x); acc.y = fmaf(w3, a3.y, acc.y);
        acc.z = fmaf(w3, b3.x, acc.z); acc.w = fmaf(w3, b3.y, acc.w);
    }

    if (active) {
        float inv = 1.f / fmaxf(ssum, 1e-20f);
        float4 bv = *(const float4*)(bias + li * 4);
        float o0 = fmaf(acc.x, inv, bv.x);
        float o1 = fmaf(acc.y, inv, bv.y);
        float o2 = fmaf(acc.z, inv, bv.z);
        float o3 = fmaf(acc.w, inv, bv.w);
        o0 = o0 > 0.f ? o0 : __expf(o0) - 1.f;
        o1 = o1 > 0.f ? o1 : __expf(o1) - 1.f;
        o2 = o2 > 0.f ? o2 : __expf(o2) - 1.f;
        o3 = o3 > 0.f ? o3 : __expf(o3) - 1.f;
        *(float4*)(out + (size_t)v * 128 + li * 4) = make_float4(o0, o1, o2, o3);
    }
}

// ---------------- launch ----------------
extern "C" void kernel_launch(void* const* d_in, const int* in_sizes, int n_in,
                              void* d_out, int out_size, void* d_ws, size_t ws_size,
                              hipStream_t stream) {
    int n_nodes = in_sizes[0] / 128;
    int n_edges = in_sizes[1];

    const float* in_feat = (const float*)d_in[0];
    const float* ew = (const float*)d_in[1];
    const int* src = (const int*)d_in[2];
    const int* dst = (const int*)d_in[3];
    const float* W0 = (const float*)d_in[4];
    const float* al0 = (const float*)d_in[5];
    const float* ar0 = (const float*)d_in[6];
    const float* b0 = (const float*)d_in[7];
    const float* W1 = (const float*)d_in[8];
    const float* al1 = (const float*)d_in[9];
    const float* ar1 = (const float*)d_in[10];
    const float* b1 = (const float*)d_in[11];
    float* out = (float*)d_out;

    char* w = (char*)d_ws;
    auto alloc = [&](size_t bytes) {
        char* p = w;
        w += (bytes + 255) & ~(size_t)255;
        return p;
    };
    __half* featH = (__half*)alloc((size_t)n_nodes * 128 * 2);  // fp16 messages
    float* h1 = (float*)alloc((size_t)n_nodes * 128 * 4);       // fp32 layer-1 out
    float* el = (float*)alloc((size_t)n_nodes * 4 * 4);
    float* er = (float*)alloc((size_t)n_nodes * 4 * 4);
    int* row_ptr = (int*)alloc(((size_t)n_nodes + 1) * 4);
    int* bcnt = (int*)alloc(MAXB * 4);
    int* boffB = (int*)alloc(MAXB * 4);
    int* bcur = (int*)alloc(MAXB * 4);
    int2* csr = (int2*)alloc((size_t)n_edges * 8 + 64);  // +pad for clamped tail reads

    // Packed staging overlays h1: staging (written k_bin, read k_buildcsr) is
    // dead before k_edge(L1) writes h1 (stream-ordered). 8B*E = 25.6MB <= 51.2MB.
    int2* recS = (int2*)h1;

    int tb = 256;
    int nb2 = (n_nodes + NPB - 1) / NPB;  // buckets (<= MAXB for n<=131072)

    // CSR build: bucketed counting sort (rebuilt every call)
    k_zero<<<(MAXB + tb - 1) / tb, tb, 0, stream>>>(bcnt, nb2);
    k_bcount<<<256, tb, 0, stream>>>(dst, bcnt, n_edges, nb2);
    k_bscan<<<1, MAXB, 0, stream>>>(bcnt, boffB, bcur, nb2);
    int a1_grid = 256;
    int chunk = (n_edges + a1_grid - 1) / a1_grid;
    k_bin<<<a1_grid, A1_BS, 0, stream>>>(src, dst, ew, bcur, recS, n_edges, chunk, nb2);
    k_buildcsr<<<nb2, MAXB, 0, stream>>>(boffB, bcnt, recS, row_ptr, csr, n_nodes, n_edges);

    dim3 gg((n_nodes + 63) / 64, 2);
    int ge = (n_nodes + 7) / 8;

    // layer 1
    k_gemm<<<gg, 256, 0, stream>>>(in_feat, W0, featH, al0, ar0, el, er, n_nodes);
    k_edge<<<ge, 256, 0, stream>>>(row_ptr, csr, featH, el, er, b0, h1, n_nodes);

    // layer 2
    k_gemm<<<gg, 256, 0, stream>>>(h1, W1, featH, al1, ar1, el, er, n_nodes);
    k_edge<<<ge, 256, 0, stream>>>(row_ptr, csr, featH, el, er, b1, out, n_nodes);
}

// Round 9
// 642.690 us; speedup vs baseline: 1.0242x; 1.0242x over previous
//
#include <hip/hip_runtime.h>
#include <hip/hip_fp16.h>
#include <math.h>

#define NEG_SLOPE 0.2f
#define NPB 256   // nodes per bucket (dst >> 8)
#define MAXB 512  // max buckets => supports n_nodes <= 131072 (bench: 100000 -> 391)
#define A1_BS 1024

static __device__ __forceinline__ float leaky(float x) { return fmaxf(x, NEG_SLOPE * x); }

// ---------------- misc ----------------
__global__ void k_zero(int* p, int n) {
    int i = blockIdx.x * blockDim.x + threadIdx.x;
    if (i < n) p[i] = 0;
}

// ---------------- bucketed counting sort CSR build ----------------
// Buckets = 256-node ranges. All heavy atomics are LDS-local; all heavy global
// writes are to per-block-exclusive contiguous ranges. Staging record is ONE
// 8B int2: word0 = src | (dst&255)<<20, word1 = ew bits. (Round-8's src-bin
// sort was NULL -- FETCH 459->455MB -- reverted: no barrier => wave drift
// destroys the locality window.)

// Pass A0: global bucket histogram (LDS pre-aggregated).
__global__ __launch_bounds__(256) void k_bcount(const int* __restrict__ dst,
                                                int* __restrict__ bcnt, int n_edges, int nb) {
    __shared__ int h[MAXB];
    for (int i = threadIdx.x; i < nb; i += blockDim.x) h[i] = 0;
    __syncthreads();
    int stride = gridDim.x * blockDim.x;
    for (int e = blockIdx.x * blockDim.x + threadIdx.x; e < n_edges; e += stride)
        atomicAdd(&h[dst[e] >> 8], 1);
    __syncthreads();
    for (int i = threadIdx.x; i < nb; i += blockDim.x)
        if (h[i]) atomicAdd(&bcnt[i], h[i]);
}

// Bucket exclusive scan (nb <= MAXB, single block).
__global__ __launch_bounds__(MAXB) void k_bscan(const int* __restrict__ bcnt,
                                                int* __restrict__ boffB,
                                                int* __restrict__ bcur, int nb) {
    __shared__ int s[MAXB];
    int t = threadIdx.x;
    int v = (t < nb) ? bcnt[t] : 0;
    s[t] = v;
    __syncthreads();
    for (int off = 1; off < MAXB; off <<= 1) {
        int x = (t >= off) ? s[t - off] : 0;
        __syncthreads();
        s[t] += x;
        __syncthreads();
    }
    if (t < nb) {
        int ex = s[t] - v;
        boffB[t] = ex;
        bcur[t] = ex;
    }
}

// Pass A1: bin edges into bucket-grouped packed staging (one int2 per edge).
__global__ __launch_bounds__(A1_BS) void k_bin(const int* __restrict__ src,
                                               const int* __restrict__ dst,
                                               const float* __restrict__ ew,
                                               int* __restrict__ bcur,
                                               int2* __restrict__ recS,
                                               int n_edges, int chunk, int nb) {
    __shared__ int cnt[MAXB];
    __shared__ int base[MAXB];
    int t = threadIdx.x;
    int e0 = blockIdx.x * chunk;
    int e1 = e0 + chunk;
    if (e1 > n_edges) e1 = n_edges;
    for (int i = t; i < nb; i += A1_BS) cnt[i] = 0;
    __syncthreads();
    for (int e = e0 + t; e < e1; e += A1_BS) atomicAdd(&cnt[dst[e] >> 8], 1);
    __syncthreads();
    for (int i = t; i < nb; i += A1_BS) {
        int c = cnt[i];
        base[i] = c ? atomicAdd(&bcur[i], c) : 0;
        cnt[i] = 0;  // reuse as local rank cursor
    }
    __syncthreads();
    for (int e = e0 + t; e < e1; e += A1_BS) {
        int d = dst[e];
        int b = d >> 8;
        int p = base[b] + atomicAdd(&cnt[b], 1);
        recS[p] = make_int2(src[e] | ((d & (NPB - 1)) << 20), __float_as_int(ew[e]));
    }
}

// Pass B (fused): per-bucket degree hist -> in-LDS scan -> row_ptr -> placement.
// One block owns its 256-node range exclusively: zero global atomics; csr
// writes land in a block-exclusive ~65KB window (full-line L2-local
// writebacks).
__global__ __launch_bounds__(NPB) void k_buildcsr(const int* __restrict__ boffB,
                                                  const int* __restrict__ bcnt,
                                                  const int2* __restrict__ recS,
                                                  int* __restrict__ row_ptr,
                                                  int2* __restrict__ csr,
                                                  int n_nodes, int n_edges) {
    __shared__ int hist[NPB];
    __shared__ int pre[NPB];
    int b = blockIdx.x;
    int t = threadIdx.x;
    hist[t] = 0;
    __syncthreads();
    int off = boffB[b];
    int end = off + bcnt[b];
    for (int i = off + t; i < end; i += NPB)
        atomicAdd(&hist[(recS[i].x >> 20) & (NPB - 1)], 1);
    __syncthreads();
    int v = hist[t];
    pre[t] = v;
    __syncthreads();
    for (int o = 1; o < NPB; o <<= 1) {
        int x = (t >= o) ? pre[t - o] : 0;
        __syncthreads();
        pre[t] += x;
        __syncthreads();
    }
    int ex = pre[t] - v;  // exclusive in-bucket prefix
    int node = b * NPB + t;
    if (node < n_nodes) row_ptr[node] = off + ex;
    if (node == n_nodes - 1) row_ptr[n_nodes] = n_edges;
    // zero pad so k_edge's clamped tail reads (deg-0 last nodes) are safe
    if (b == 0 && t < 8) csr[n_edges + t] = make_int2(0, 0);
    hist[t] = off + ex;  // reuse as cursor
    __syncthreads();
    for (int i = off + t; i < end; i += NPB) {
        int2 r = recS[i];
        int dl = (r.x >> 20) & (NPB - 1);
        int p = atomicAdd(&hist[dl], 1);
        csr[p] = make_int2(r.x & 0xFFFFF, r.y);
    }
}

// ---------------- GEMM + fused attention scores ----------------
// 128x128 tile, 8x8 per thread, single y-block. Previous 64x64/4x4 tile was
// LDS-read bound (128 ds_read_b128 vs 512 fma per thread = 1536:1024 cyc) and
// read A twice (y=2). Now: B reused 8x per LDS read (96:512 -> VALU-bound at
// the 21us/gemm fma floor), A read once. B staged as two 32KB half-K strips.
// C is fp16 (messages consumed only by k_edge's gather); el/er from fp32 acc.
__global__ __launch_bounds__(256) void k_gemm(const float* __restrict__ A,
                                              const float* __restrict__ B,
                                              __half* __restrict__ C,
                                              const float* __restrict__ al,
                                              const float* __restrict__ ar,
                                              float* __restrict__ el,
                                              float* __restrict__ er, int n) {
    __shared__ float Bs[64 * 128];  // half-K strip Bs[k][c], 32KB
    int t = threadIdx.x;
    int row0 = blockIdx.x * 128;
    int rbase = row0 + (t >> 4) * 8;  // 8 rows per thread
    int ci = t & 15;
    int c0 = ci * 8;                  // 8 cols per thread
    int h = ci >> 2;                  // head of this col block

    int rc[8];
#pragma unroll
    for (int i = 0; i < 8; ++i) rc[i] = (rbase + i < n) ? rbase + i : 0;

    float acc[8][8];
#pragma unroll
    for (int i = 0; i < 8; ++i)
#pragma unroll
        for (int j = 0; j < 8; ++j) acc[i][j] = 0.f;

#pragma unroll
    for (int kh = 0; kh < 2; ++kh) {
        // stage B[kh*64 .. +63][0..127]: 2048 float4 / 256 threads = 8 each
        {
            int cc = (t & 31) * 4;
            int kr = t >> 5;  // 0..7
#pragma unroll
            for (int it = 0; it < 8; ++it) {
                int k = kr + it * 8;
                *(float4*)(Bs + k * 128 + cc) =
                    *(const float4*)(B + (size_t)(kh * 64 + k) * 128 + cc);
            }
        }
        __syncthreads();

        for (int k4 = 0; k4 < 64; k4 += 4) {
            float4 av[8];
#pragma unroll
            for (int i = 0; i < 8; ++i)
                av[i] = *(const float4*)(A + (size_t)rc[i] * 128 + kh * 64 + k4);
#pragma unroll
            for (int kk = 0; kk < 4; ++kk) {
                float4 b0 = *(const float4*)(Bs + (k4 + kk) * 128 + c0);
                float4 b1 = *(const float4*)(Bs + (k4 + kk) * 128 + c0 + 4);
#pragma unroll
                for (int i = 0; i < 8; ++i) {
                    float e = kk == 0 ? av[i].x : kk == 1 ? av[i].y : kk == 2 ? av[i].z : av[i].w;
                    acc[i][0] = fmaf(e, b0.x, acc[i][0]);
                    acc[i][1] = fmaf(e, b0.y, acc[i][1]);
                    acc[i][2] = fmaf(e, b0.z, acc[i][2]);
                    acc[i][3] = fmaf(e, b0.w, acc[i][3]);
                    acc[i][4] = fmaf(e, b1.x, acc[i][4]);
                    acc[i][5] = fmaf(e, b1.y, acc[i][5]);
                    acc[i][6] = fmaf(e, b1.z, acc[i][6]);
                    acc[i][7] = fmaf(e, b1.w, acc[i][7]);
                }
            }
        }
        __syncthreads();
    }

    // store fp16: 8 contiguous halves = 16B per row
#pragma unroll
    for (int i = 0; i < 8; ++i) {
        int r = rbase + i;
        if (r < n) {
            union { __half2 hh[4]; uint4 u; } cv;
            cv.hh[0] = __floats2half2_rn(acc[i][0], acc[i][1]);
            cv.hh[1] = __floats2half2_rn(acc[i][2], acc[i][3]);
            cv.hh[2] = __floats2half2_rn(acc[i][4], acc[i][5]);
            cv.hh[3] = __floats2half2_rn(acc[i][6], acc[i][7]);
            *(uint4*)(C + (size_t)r * 128 + c0) = cv.u;
        }
    }

    // fused el/er: 4 lanes (ci & 3) per (row-group, head); shfl_xor 1,2 reduce.
    {
        int coff = h * 32 + (c0 & 31);
        float4 a4a = *(const float4*)(al + coff);
        float4 a4b = *(const float4*)(al + coff + 4);
        float4 b4a = *(const float4*)(ar + coff);
        float4 b4b = *(const float4*)(ar + coff + 4);
        float pel[8], per[8];
#pragma unroll
        for (int i = 0; i < 8; ++i) {
            pel[i] = acc[i][0] * a4a.x + acc[i][1] * a4a.y + acc[i][2] * a4a.z + acc[i][3] * a4a.w +
                     acc[i][4] * a4b.x + acc[i][5] * a4b.y + acc[i][6] * a4b.z + acc[i][7] * a4b.w;
            per[i] = acc[i][0] * b4a.x + acc[i][1] * b4a.y + acc[i][2] * b4a.z + acc[i][3] * b4a.w +
                     acc[i][4] * b4b.x + acc[i][5] * b4b.y + acc[i][6] * b4b.z + acc[i][7] * b4b.w;
        }
#pragma unroll
        for (int m = 1; m < 4; m <<= 1) {
#pragma unroll
            for (int i = 0; i < 8; ++i) {
                pel[i] += __shfl_xor(pel[i], m);
                per[i] += __shfl_xor(per[i], m);
            }
        }
        if ((ci & 3) == 0) {
#pragma unroll
            for (int i = 0; i < 8; ++i) {
                int r = rbase + i;
                if (r < n) {
                    el[(size_t)r * 4 + h] = pel[i];
                    er[(size_t)r * 4 + h] = per[i];
                }
            }
        }
    }
}

// ---------------- per-dst-node softmax + aggregate (fp16 gather) ----------
// At its structural ceiling: 455MB beyond-L2 at ~3.5TB/s = 130 of 147us
// (8 structural variants, rounds 0-8). Lane li reads 8B (uint2 = 4 halves);
// 32 lanes x 8B = 256B contiguous per edge.
__global__ __launch_bounds__(256) void k_edge(const int* __restrict__ row_ptr,
                                              const int2* __restrict__ csr,
                                              const __half* __restrict__ feat,
                                              const float* __restrict__ el,
                                              const float* __restrict__ er,
                                              const float* __restrict__ bias,
                                              float* __restrict__ out, int n) {
    int wv = threadIdx.x >> 6;
    int lane = threadIdx.x & 63;
    int sub = lane >> 5;   // which node of this wave's pair
    int li = lane & 31;    // feature lane
    int h = li >> 3;       // head
    int v = blockIdx.x * 8 + wv * 2 + sub;
    bool active = v < n;
    int vc = active ? v : n - 1;

    int start = row_ptr[vc];
    int end = active ? row_ptr[vc + 1] : start;
    float er_h = er[(size_t)vc * 4 + h];

    int myT = (end - start + 3) >> 2;
    int otherT = __shfl(myT, lane ^ 32);
    int maxT = myT > otherT ? myT : otherT;

    int last = end - 1;
    if (last < start) last = start;  // deg-0 half: clamped reads (csr pad is zeroed)

    float4 acc = make_float4(0.f, 0.f, 0.f, 0.f);
    float ssum = 0.f;

    for (int j = 0; j < maxT; ++j) {
        int i = start + j * 4;
        int i0 = i < last ? i : last;
        int i1 = i + 1 < last ? i + 1 : last;
        int i2 = i + 2 < last ? i + 2 : last;
        int i3 = i + 3 < last ? i + 3 : last;
        float m0 = (i < end) ? 1.f : 0.f;
        float m1 = (i + 1 < end) ? 1.f : 0.f;
        float m2 = (i + 2 < end) ? 1.f : 0.f;
        float m3 = (i + 3 < end) ? 1.f : 0.f;
        int2 c0 = csr[i0];
        int2 c1 = csr[i1];
        int2 c2 = csr[i2];
        int2 c3 = csr[i3];
        // all independent loads first (4-deep MLP)
        float el0 = el[(size_t)c0.x * 4 + h];
        float el1 = el[(size_t)c1.x * 4 + h];
        float el2 = el[(size_t)c2.x * 4 + h];
        float el3 = el[(size_t)c3.x * 4 + h];
        uint2 r0 = ((const uint2*)(feat + (size_t)c0.x * 128))[li];
        uint2 r1 = ((const uint2*)(feat + (size_t)c1.x * 128))[li];
        uint2 r2 = ((const uint2*)(feat + (size_t)c2.x * 128))[li];
        uint2 r3 = ((const uint2*)(feat + (size_t)c3.x * 128))[li];
        float p0 = m0 * __expf(leaky(el0 + er_h));
        float p1 = m1 * __expf(leaky(el1 + er_h));
        float p2 = m2 * __expf(leaky(el2 + er_h));
        float p3 = m3 * __expf(leaky(el3 + er_h));
        ssum += (p0 + p1) + (p2 + p3);
        float w0 = p0 * __int_as_float(c0.y);
        float w1 = p1 * __int_as_float(c1.y);
        float w2 = p2 * __int_as_float(c2.y);
        float w3 = p3 * __int_as_float(c3.y);
        float2 a0 = __half22float2(*(__half2*)&r0.x);
        float2 b0 = __half22float2(*(__half2*)&r0.y);
        float2 a1 = __half22float2(*(__half2*)&r1.x);
        float2 b1 = __half22float2(*(__half2*)&r1.y);
        float2 a2 = __half22float2(*(__half2*)&r2.x);
        float2 b2 = __half22float2(*(__half2*)&r2.y);
        float2 a3 = __half22float2(*(__half2*)&r3.x);
        float2 b3 = __half22float2(*(__half2*)&r3.y);
        acc.x = fmaf(w0, a0.x, acc.x); acc.y = fmaf(w0, a0.y, acc.y);
        acc.z = fmaf(w0, b0.x, acc.z); acc.w = fmaf(w0, b0.y, acc.w);
        acc.x = fmaf(w1, a1.x, acc.x); acc.y = fmaf(w1, a1.y, acc.y);
        acc.z = fmaf(w1, b1.x, acc.z); acc.w = fmaf(w1, b1.y, acc.w);
        acc.x = fmaf(w2, a2.x, acc.x); acc.y = fmaf(w2, a2.y, acc.y);
        acc.z = fmaf(w2, b2.x, acc.z); acc.w = fmaf(w2, b2.y, acc.w);
        acc.x = fmaf(w3, a3.x, acc.x); acc.y = fmaf(w3, a3.y, acc.y);
        acc.z = fmaf(w3, b3.x, acc.z); acc.w = fmaf(w3, b3.y, acc.w);
    }

    if (active) {
        float inv = 1.f / fmaxf(ssum, 1e-20f);
        float4 bv = *(const float4*)(bias + li * 4);
        float o0 = fmaf(acc.x, inv, bv.x);
        float o1 = fmaf(acc.y, inv, bv.y);
        float o2 = fmaf(acc.z, inv, bv.z);
        float o3 = fmaf(acc.w, inv, bv.w);
        o0 = o0 > 0.f ? o0 : __expf(o0) - 1.f;
        o1 = o1 > 0.f ? o1 : __expf(o1) - 1.f;
        o2 = o2 > 0.f ? o2 : __expf(o2) - 1.f;
        o3 = o3 > 0.f ? o3 : __expf(o3) - 1.f;
        *(float4*)(out + (size_t)v * 128 + li * 4) = make_float4(o0, o1, o2, o3);
    }
}

// ---------------- launch ----------------
extern "C" void kernel_launch(void* const* d_in, const int* in_sizes, int n_in,
                              void* d_out, int out_size, void* d_ws, size_t ws_size,
                              hipStream_t stream) {
    int n_nodes = in_sizes[0] / 128;
    int n_edges = in_sizes[1];

    const float* in_feat = (const float*)d_in[0];
    const float* ew = (const float*)d_in[1];
    const int* src = (const int*)d_in[2];
    const int* dst = (const int*)d_in[3];
    const float* W0 = (const float*)d_in[4];
    const float* al0 = (const float*)d_in[5];
    const float* ar0 = (const float*)d_in[6];
    const float* b0 = (const float*)d_in[7];
    const float* W1 = (const float*)d_in[8];
    const float* al1 = (const float*)d_in[9];
    const float* ar1 = (const float*)d_in[10];
    const float* b1 = (const float*)d_in[11];
    float* out = (float*)d_out;

    char* w = (char*)d_ws;
    auto alloc = [&](size_t bytes) {
        char* p = w;
        w += (bytes + 255) & ~(size_t)255;
        return p;
    };
    __half* featH = (__half*)alloc((size_t)n_nodes * 128 * 2);  // fp16 messages
    float* h1 = (float*)alloc((size_t)n_nodes * 128 * 4);       // fp32 layer-1 out
    float* el = (float*)alloc((size_t)n_nodes * 4 * 4);
    float* er = (float*)alloc((size_t)n_nodes * 4 * 4);
    int* row_ptr = (int*)alloc(((size_t)n_nodes + 1) * 4);
    int* bcnt = (int*)alloc(MAXB * 4);
    int* boffB = (int*)alloc(MAXB * 4);
    int* bcur = (int*)alloc(MAXB * 4);
    int2* csr = (int2*)alloc((size_t)n_edges * 8 + 64);  // +pad for clamped tail reads

    // Packed staging overlays h1: staging (written k_bin, read k_buildcsr) is
    // dead before k_edge(L1) writes h1 (stream-ordered). 8B*E = 25.6MB <= 51.2MB.
    int2* recS = (int2*)h1;

    int tb = 256;
    int nb2 = (n_nodes + NPB - 1) / NPB;  // buckets (<= MAXB for n<=131072)

    // CSR build: bucketed counting sort (rebuilt every call)
    k_zero<<<(MAXB + tb - 1) / tb, tb, 0, stream>>>(bcnt, nb2);
    k_bcount<<<256, tb, 0, stream>>>(dst, bcnt, n_edges, nb2);
    k_bscan<<<1, MAXB, 0, stream>>>(bcnt, boffB, bcur, nb2);
    int a1_grid = 256;
    int chunk = (n_edges + a1_grid - 1) / a1_grid;
    k_bin<<<a1_grid, A1_BS, 0, stream>>>(src, dst, ew, bcur, recS, n_edges, chunk, nb2);
    k_buildcsr<<<nb2, NPB, 0, stream>>>(boffB, bcnt, recS, row_ptr, csr, n_nodes, n_edges);

    int gg = (n_nodes + 127) / 128;
    int ge = (n_nodes + 7) / 8;

    // layer 1
    k_gemm<<<gg, 256, 0, stream>>>(in_feat, W0, featH, al0, ar0, el, er, n_nodes);
    k_edge<<<ge, 256, 0, stream>>>(row_ptr, csr, featH, el, er, b0, h1, n_nodes);

    // layer 2
    k_gemm<<<gg, 256, 0, stream>>>(h1, W1, featH, al1, ar1, el, er, n_nodes);
    k_edge<<<ge, 256, 0, stream>>>(row_ptr, csr, featH, el, er, b1, out, n_nodes);
}